// Round 17
// baseline (181.417 us; speedup 1.0000x reference)
//
#include <hip/hip_runtime.h>
#include <hip/hip_fp16.h>
#include <math.h>

#define T_TOKENS 16384
#define D_DIM    2048
#define NEXP     256
#define TOPK     8
#define NLIM     4
#define BM       16           // block: 16 tokens x 256 experts; grid 1024
#define KSTEPS   32           // K-step = 64 (two 32-chunks)
#define NTHREADS 512          // 8 waves; wave = 16 tok x 32 exp

typedef __attribute__((ext_vector_type(8))) _Float16 f16x8;  // 4 VGPRs
typedef __attribute__((ext_vector_type(4))) float f32x4;     // MFMA acc

// ---- pre-pass: w[256][2048] f32 -> fp16 in MFMA-fragment order ----
// wf layout (fp16): [kc(64)][nfg(16)][lane(64)][j(8)]   (kc = 32-wide k chunk)
// value = (half) w[ e = nfg*16 + (lane&15) ][ k = kc*32 + (lane>>4)*8 + j ]
__global__ __launch_bounds__(256) void prep_w(const float* __restrict__ w,
                                              unsigned short* __restrict__ wf) {
  const int g   = blockIdx.x * 256 + threadIdx.x;  // 0..65535
  const int kc  = g >> 10;
  const int rem = g & 1023;
  const int nfg = rem >> 6;
  const int l   = rem & 63;
  const int e   = nfg * 16 + (l & 15);
  const int kb  = kc * 32 + ((l >> 4) << 3);
  const float* src = &w[(size_t)e * D_DIM + kb];
  float f[8];
  *reinterpret_cast<float4*>(&f[0]) = *reinterpret_cast<const float4*>(src);
  *reinterpret_cast<float4*>(&f[4]) = *reinterpret_cast<const float4*>(src + 4);
  union { unsigned short s[8]; float4 v; } h;
  #pragma unroll
  for (int j = 0; j < 8; ++j) h.s[j] = __half_as_ushort(__float2half(f[j]));
  *reinterpret_cast<float4*>(wf + (size_t)kc * 8192 + nfg * 512 + l * 8) = h.v;
}

__device__ __forceinline__ unsigned cvt2(float a, float b) {  // RNE
  return (unsigned)__half_as_ushort(__float2half(a)) |
         ((unsigned)__half_as_ushort(__float2half(b)) << 16);
}
__device__ __forceinline__ f16x8 cvt8(const float4& lo, const float4& hi) {
  union { unsigned u[4]; f16x8 v; } h;
  h.u[0] = cvt2(lo.x, lo.y); h.u[1] = cvt2(lo.z, lo.w);
  h.u[2] = cvt2(hi.x, hi.y); h.u[3] = cvt2(hi.z, hi.w);
  return h.v;
}

// one pipeline ring: A raw f32 (4 x float4) + B fp16 (4 x f16x8), 32 VGPR
struct Ring {
  float4 a[4];   // chunk0 lo,hi ; chunk1 lo,hi
  f16x8  b[4];   // chunk0 nf0,nf1 ; chunk1 nf0,nf1
};

__device__ __forceinline__ void ring_load(Ring& r, int t, const float* xp,
                                          const unsigned short* wfB) {
  const int kt = (t < KSTEPS) ? t : KSTEPS - 1;
  const float* xa = xp + (size_t)kt * 64;
  r.a[0] = *reinterpret_cast<const float4*>(xa);
  r.a[1] = *reinterpret_cast<const float4*>(xa + 4);
  r.a[2] = *reinterpret_cast<const float4*>(xa + 32);
  r.a[3] = *reinterpret_cast<const float4*>(xa + 36);
  const unsigned short* wb = wfB + (size_t)kt * 16384;
  r.b[0] = *reinterpret_cast<const f16x8*>(wb);
  r.b[1] = *reinterpret_cast<const f16x8*>(wb + 512);
  r.b[2] = *reinterpret_cast<const f16x8*>(wb + 8192);
  r.b[3] = *reinterpret_cast<const f16x8*>(wb + 8704);
}

// keep-alive pin. SCALAR operands only (hipcc rejects vector asm operands).
// One 32-bit component per loaded vector: a dwordx4 load completes as a unit,
// so pinning .x forces the whole load's waitcnt here and blocks sinking.
__device__ __forceinline__ void pin(const Ring& r) {
  uint4 b0 = __builtin_bit_cast(uint4, r.b[0]);
  uint4 b1 = __builtin_bit_cast(uint4, r.b[1]);
  uint4 b2 = __builtin_bit_cast(uint4, r.b[2]);
  uint4 b3 = __builtin_bit_cast(uint4, r.b[3]);
  asm volatile("" :: "v"(r.a[0].x), "v"(r.a[1].x), "v"(r.a[2].x), "v"(r.a[3].x),
                     "v"(b0.x), "v"(b1.x), "v"(b2.x), "v"(b3.x));
}

// body t: issue loads(t+2)->n2 ; compute(cur=t) ; PIN n1 (loaded t-1, used t+1)
__device__ __forceinline__ void body(
    int t, const float* xp, const unsigned short* wfB,
    Ring& cur, Ring& n1, Ring& n2, f32x4 (&acc)[2]) {
  ring_load(n2, t + 2, xp, wfB);
  __builtin_amdgcn_sched_barrier(0);
  f16x8 a0 = cvt8(cur.a[0], cur.a[1]);
  acc[0] = __builtin_amdgcn_mfma_f32_16x16x32_f16(a0, cur.b[0], acc[0], 0, 0, 0);
  acc[1] = __builtin_amdgcn_mfma_f32_16x16x32_f16(a0, cur.b[1], acc[1], 0, 0, 0);
  f16x8 a1 = cvt8(cur.a[2], cur.a[3]);
  acc[0] = __builtin_amdgcn_mfma_f32_16x16x32_f16(a1, cur.b[2], acc[0], 0, 0, 0);
  acc[1] = __builtin_amdgcn_mfma_f32_16x16x32_f16(a1, cur.b[3], acc[1], 0, 0, 0);
  __builtin_amdgcn_sched_barrier(0);
  pin(n1);
  __builtin_amdgcn_sched_barrier(0);
}

// ---- fused GEMM: LDS-free, barrier-free, asm-pinned 3-ring pipeline ----
__global__ __launch_bounds__(NTHREADS, 4) void gate_kernel(
    const float* __restrict__ x,
    const unsigned short* __restrict__ wf,
    const float* __restrict__ bias,
    float* __restrict__ out_w,
    float* __restrict__ out_idx,
    float* __restrict__ out_load) {

  __shared__ float Sc[BM][260];
  __shared__ int hist[NEXP];

  const int tid  = threadIdx.x;
  const int row0 = blockIdx.x * BM;
  const int lane = tid & 63;
  const int wid  = tid >> 6;   // 0..7 ; wave owns experts wid*32..wid*32+31

  for (int i = tid; i < NEXP; i += NTHREADS) hist[i] = 0;

  // per-lane A source: row = row0 + (lane&15), k = kc*32 + (lane>>4)*8 + j
  const float* xp =
      &x[(size_t)(row0 + (lane & 15)) * D_DIM + ((lane >> 4) << 3)];
  // per-lane B source (fragment-linear wf); wave covers nfg = wid*2, wid*2+1
  const unsigned short* wfB = wf + (size_t)(wid * 2) * 512 + (size_t)lane * 8;

  f32x4 acc[2];
  acc[0] = (f32x4)(0.0f);
  acc[1] = (f32x4)(0.0f);

  Ring R0, R1, R2;
  ring_load(R0, 0, xp, wfB);
  ring_load(R1, 1, xp, wfB);

  for (int t = 0; t < 30; t += 3) {
    body(t,     xp, wfB, R0, R1, R2, acc);
    body(t + 1, xp, wfB, R1, R2, R0, acc);
    body(t + 2, xp, wfB, R2, R0, R1, acc);
  }
  body(30, xp, wfB, R0, R1, R2, acc);
  body(31, xp, wfB, R1, R2, R0, acc);

  // ---- epilogue: logits -> Sc (C/D layout: col=lane&15, row=(lane>>4)*4+r)
  #pragma unroll
  for (int nf = 0; nf < 2; ++nf)
    #pragma unroll
    for (int r = 0; r < 4; ++r) {
      const int row = ((lane >> 4) << 2) + r;
      const int col = wid * 32 + nf * 16 + (lane & 15);
      Sc[row][col] = acc[nf][r];
    }
  __syncthreads();

  // ---- routing: one wave per token, lane holds experts 4l..4l+3
  const float4 bsl = *reinterpret_cast<const float4*>(&bias[lane * 4]);
  const int g = lane >> 3;   // group of this lane's experts

  for (int m = wid; m < BM; m += 8) {
    float v[4];
    *reinterpret_cast<float4*>(v) =
        *reinterpret_cast<const float4*>(&Sc[m][lane * 4]);

    // softmax (match jax: subtract row max, exp, divide by sum)
    float mx = fmaxf(fmaxf(v[0], v[1]), fmaxf(v[2], v[3]));
    #pragma unroll
    for (int s = 1; s < 64; s <<= 1) mx = fmaxf(mx, __shfl_xor(mx, s));
    float ex[4], sum = 0.f;
    #pragma unroll
    for (int j = 0; j < 4; ++j) { ex[j] = expf(v[j] - mx); sum += ex[j]; }
    #pragma unroll
    for (int s = 1; s < 64; s <<= 1) sum += __shfl_xor(sum, s);
    float sc[4], sel[4];
    sc[0] = ex[0] / sum; sc[1] = ex[1] / sum;
    sc[2] = ex[2] / sum; sc[3] = ex[3] / sum;
    sel[0] = sc[0] + bsl.x; sel[1] = sc[1] + bsl.y;
    sel[2] = sc[2] + bsl.z; sel[3] = sc[3] + bsl.w;

    // keep original scores for the gather
    *reinterpret_cast<float4*>(&Sc[m][lane * 4]) =
        make_float4(sc[0], sc[1], sc[2], sc[3]);

    // group max (groups of 32 experts = 8 lanes)
    float gv = fmaxf(fmaxf(sel[0], sel[1]), fmaxf(sel[2], sel[3]));
    gv = fmaxf(gv, __shfl_xor(gv, 1));
    gv = fmaxf(gv, __shfl_xor(gv, 2));
    gv = fmaxf(gv, __shfl_xor(gv, 4));

    // top-4 groups, tie -> lower group index (jax.lax.top_k stability)
    unsigned gmask = 0;
    float gcur = gv;
    #pragma unroll
    for (int it = 0; it < NLIM; ++it) {
      float bv2 = gcur; int bi = g;
      #pragma unroll
      for (int s = 1; s < 64; s <<= 1) {
        float ov = __shfl_xor(bv2, s);
        int   oi = __shfl_xor(bi, s);
        if (ov > bv2 || (ov == bv2 && oi < bi)) { bv2 = ov; bi = oi; }
      }
      gmask |= 1u << bi;
      if (g == bi) gcur = -INFINITY;
    }
    if (!((gmask >> g) & 1u)) {
      sel[0] = sel[1] = sel[2] = sel[3] = -INFINITY;
    }

    // top-8 experts, tie -> lower expert index
    const int gtok = row0 + m;
    #pragma unroll
    for (int it = 0; it < TOPK; ++it) {
      float bv2 = sel[0]; int bi = lane * 4;
      #pragma unroll
      for (int j = 1; j < 4; ++j)
        if (sel[j] > bv2) { bv2 = sel[j]; bi = lane * 4 + j; }
      #pragma unroll
      for (int s = 1; s < 64; s <<= 1) {
        float ov = __shfl_xor(bv2, s);
        int   oi = __shfl_xor(bi, s);
        if (ov > bv2 || (ov == bv2 && oi < bi)) { bv2 = ov; bi = oi; }
      }
      if (lane == 0) {
        out_w[(size_t)gtok * TOPK + it]   = Sc[m][bi] * 2.5f;
        out_idx[(size_t)gtok * TOPK + it] = (float)bi;
        atomicAdd(&hist[bi], 1);
      }
      if ((bi >> 2) == lane) sel[bi & 3] = -INFINITY;
    }
  }

  __syncthreads();
  for (int b = tid; b < NEXP; b += NTHREADS)
    if (hist[b]) atomicAdd(&out_load[b], (float)hist[b]);
}

extern "C" void kernel_launch(void* const* d_in, const int* in_sizes, int n_in,
                              void* d_out, int out_size, void* d_ws, size_t ws_size,
                              hipStream_t stream) {
  const float* x    = (const float*)d_in[0];
  const float* w    = (const float*)d_in[1];
  const float* bias = (const float*)d_in[2];
  float* out_w    = (float*)d_out;
  float* out_idx  = out_w + (size_t)T_TOKENS * TOPK;
  float* out_load = out_idx + (size_t)T_TOKENS * TOPK;
  unsigned short* wfrag = (unsigned short*)d_ws;   // 1 MB fragment-ordered fp16 w

  (void)hipMemsetAsync(out_load, 0, NEXP * sizeof(float), stream);
  prep_w<<<256, 256, 0, stream>>>(w, wfrag);
  gate_kernel<<<T_TOKENS / BM, NTHREADS, 0, stream>>>(
      x, wfrag, bias, out_w, out_idx, out_load);
}

// Round 18
// 105.552 us; speedup vs baseline: 1.7187x; 1.7187x over previous
//
#include <hip/hip_runtime.h>
#include <hip/hip_fp16.h>
#include <math.h>

#define T_TOKENS 16384
#define D_DIM    2048
#define NEXP     256
#define TOPK     8
#define NLIM     4
#define BM       32
#define NSS      16          // supersteps, BK=128 each (4 sub-k of 32)
#define NTHREADS 512

typedef __attribute__((ext_vector_type(8))) _Float16 f16x8;  // 4 VGPRs
typedef __attribute__((ext_vector_type(4))) float f32x4;     // MFMA acc

// LDS: A = fp16 x-fragments, 2-ring dbuf (8 KB/ring); Sc aliases after GEMM.
//  A[ring][ks(4)][mf(2)][lane(64)][j(8 fp16)] : frag-linear, 16B granules
struct GemmBufs { unsigned short A[2][4][2][64][8]; };  // 16 KB
union SMem {
  GemmBufs g;
  float Sc[BM][260];                                    // 33.3 KB
};

// ---- pre-pass: w[256][2048] f32 -> fp16 in MFMA-fragment order ----
// wf layout (fp16): [kc(64)][nfg(16)][lane(64)][j(8)]
// value = (half) w[ e = nfg*16 + (lane&15) ][ k = kc*32 + (lane>>4)*8 + j ]
__global__ __launch_bounds__(256) void prep_w(const float* __restrict__ w,
                                              unsigned short* __restrict__ wf) {
  const int g   = blockIdx.x * 256 + threadIdx.x;  // 0..65535
  const int kc  = g >> 10;
  const int rem = g & 1023;
  const int nfg = rem >> 6;
  const int l   = rem & 63;
  const int e   = nfg * 16 + (l & 15);
  const int kb  = kc * 32 + ((l >> 4) << 3);
  const float* src = &w[(size_t)e * D_DIM + kb];
  float f[8];
  *reinterpret_cast<float4*>(&f[0]) = *reinterpret_cast<const float4*>(src);
  *reinterpret_cast<float4*>(&f[4]) = *reinterpret_cast<const float4*>(src + 4);
  union { unsigned short s[8]; float4 v; } h;
  #pragma unroll
  for (int j = 0; j < 8; ++j) h.s[j] = __half_as_ushort(__float2half(f[j]));
  *reinterpret_cast<float4*>(wf + (size_t)kc * 8192 + nfg * 512 + l * 8) = h.v;
}

__device__ __forceinline__ unsigned cvt2(float a, float b) {  // RNE pair
  return (unsigned)__half_as_ushort(__float2half(a)) |
         ((unsigned)__half_as_ushort(__float2half(b)) << 16);
}
__device__ __forceinline__ uint4 pack8(const float4& lo, const float4& hi) {
  uint4 p;
  p.x = cvt2(lo.x, lo.y); p.y = cvt2(lo.z, lo.w);
  p.z = cvt2(hi.x, hi.y); p.w = cvt2(hi.z, hi.w);
  return p;
}

// ---- one superstep ----
// (1) issue x(n+2)->xn ; (2) B(n)->regs ; (3) ds_read A(n) frags + 16 MFMA ;
// (4) cvt x(n+1) (in xc) -> ds_write ring n^1 ; (5) lgkmcnt(0) + barrier.
// No gll, no manual vmcnt: every VMEM dep is a register dep.
__device__ __forceinline__ void body(
    int n, const float* asrc, const unsigned short* wfB,
    int ksw, int mfw, int lnw, int lane,
    float4& xc0, float4& xc1,    // holds x(n+1)
    float4& xn0, float4& xn1,    // receives x(n+2)
    SMem& sm, f32x4 (&acc)[2][2]) {
  // (1) prefetch x(n+2): one full superstep of flight
  if (n + 2 < NSS) {
    const float* s = asrc + (size_t)(n + 2) * 128;
    xn0 = *reinterpret_cast<const float4*>(s);
    xn1 = *reinterpret_cast<const float4*>(s + 4);
  }
  __builtin_amdgcn_sched_barrier(0);
  // (2) B(n): 8 dwordx4 into regs (wave-private, L2-hot)
  f16x8 b[2][4];
  #pragma unroll
  for (int nf = 0; nf < 2; ++nf)
    #pragma unroll
    for (int ks = 0; ks < 4; ++ks)
      b[nf][ks] = *reinterpret_cast<const f16x8*>(
          wfB + (size_t)(n * 4 + ks) * 8192 + nf * 512);
  // (3) A(n) frags from LDS (fp16, direct) + MFMA
  const int ring = n & 1;
  f16x8 a[2][4];
  #pragma unroll
  for (int mf = 0; mf < 2; ++mf)
    #pragma unroll
    for (int ks = 0; ks < 4; ++ks)
      a[mf][ks] = *reinterpret_cast<const f16x8*>(&sm.g.A[ring][ks][mf][lane][0]);
  #pragma unroll
  for (int ks = 0; ks < 4; ++ks)
    #pragma unroll
    for (int mf = 0; mf < 2; ++mf) {
      acc[mf][0] = __builtin_amdgcn_mfma_f32_16x16x32_f16(a[mf][ks], b[0][ks], acc[mf][0], 0, 0, 0);
      acc[mf][1] = __builtin_amdgcn_mfma_f32_16x16x32_f16(a[mf][ks], b[1][ks], acc[mf][1], 0, 0, 0);
    }
  __builtin_amdgcn_sched_barrier(0);
  // (4) stage x(n+1) -> ring^1 (cvt once/elem; linear 16B/thread: conflict-free)
  if (n + 1 < NSS) {
    uint4 p = pack8(xc0, xc1);
    *reinterpret_cast<uint4*>(&sm.g.A[ring ^ 1][ksw][mfw][lnw][0]) = p;
  }
  // (5) LDS-only barrier (x prefetch stays in flight)
  asm volatile("s_waitcnt lgkmcnt(0)" ::: "memory");
  __builtin_amdgcn_sched_barrier(0);
  __builtin_amdgcn_s_barrier();
  __builtin_amdgcn_sched_barrier(0);
}

// ---- fused GEMM (fp16 MFMA; A reg->cvt->ds_write dbuf; B in regs) ----
__global__ __launch_bounds__(NTHREADS, 4) void gate_kernel(
    const float* __restrict__ x,
    const unsigned short* __restrict__ wf,
    const float* __restrict__ bias,
    float* __restrict__ out_w,
    float* __restrict__ out_idx,
    float* __restrict__ out_load) {

  __shared__ SMem sm;
  __shared__ int hist[NEXP];

  const int tid  = threadIdx.x;
  const int row0 = blockIdx.x * BM;
  const int lane = tid & 63;
  const int wid  = tid >> 6;   // 0..7 ; wave owns experts wid*32..wid*32+31

  for (int i = tid; i < NEXP; i += NTHREADS) hist[i] = 0;

  // A staging map: thread owns fragment-slot tid = [ksw][mfw][lnw] (16B)
  // source: 32B contiguous = x[row0+mfw*16+(lnw&15)][ksw*32+(lnw>>4)*8 .. +7]
  // -> wave covers exactly 16 full 128B lines (perfect coalescing)
  const int ksw = tid >> 7;
  const int mfw = (tid >> 6) & 1;
  const int lnw = tid & 63;
  const float* asrc = &x[(size_t)(row0 + mfw * 16 + (lnw & 15)) * D_DIM +
                         ksw * 32 + ((lnw >> 4) << 3)];
  // B source base (fragment-linear wf)
  const unsigned short* wfB = wf + (size_t)(wid * 2) * 512 + (size_t)lane * 8;

  f32x4 acc[2][2];
  #pragma unroll
  for (int i = 0; i < 2; ++i)
    #pragma unroll
    for (int j = 0; j < 2; ++j) acc[i][j] = (f32x4)(0.0f);

  // ---- prologue: stage superstep 0 into ring 0; prefetch x(1)
  float4 xA0, xA1, xB0, xB1;
  {
    float4 p0 = *reinterpret_cast<const float4*>(asrc);
    float4 p1 = *reinterpret_cast<const float4*>(asrc + 4);
    xA0 = *reinterpret_cast<const float4*>(asrc + 128);   // x(1)
    xA1 = *reinterpret_cast<const float4*>(asrc + 132);
    uint4 p = pack8(p0, p1);
    *reinterpret_cast<uint4*>(&sm.g.A[0][ksw][mfw][lnw][0]) = p;
  }
  asm volatile("s_waitcnt lgkmcnt(0)" ::: "memory");
  __builtin_amdgcn_sched_barrier(0);
  __builtin_amdgcn_s_barrier();
  __builtin_amdgcn_sched_barrier(0);

  // ---- 16 supersteps (unroll 2 for xr ping-pong static names)
  for (int n = 0; n < NSS; n += 2) {
    body(n,     asrc, wfB, ksw, mfw, lnw, lane, xA0, xA1, xB0, xB1, sm, acc);
    body(n + 1, asrc, wfB, ksw, mfw, lnw, lane, xB0, xB1, xA0, xA1, sm, acc);
  }
  __syncthreads();   // full drain; safe to alias Sc over A

  // ---- epilogue: logits -> Sc (C/D layout: col=lane&15, row=(lane>>4)*4+r)
  #pragma unroll
  for (int mf = 0; mf < 2; ++mf)
    #pragma unroll
    for (int nf = 0; nf < 2; ++nf)
      #pragma unroll
      for (int r = 0; r < 4; ++r) {
        const int row = mf * 16 + ((lane >> 4) << 2) + r;
        const int col = wid * 32 + nf * 16 + (lane & 15);
        sm.Sc[row][col] = acc[mf][nf][r];
      }
  __syncthreads();

  // ---- routing: one wave per token, lane holds experts 4l..4l+3
  const float4 bsl = *reinterpret_cast<const float4*>(&bias[lane * 4]);
  const int g = lane >> 3;   // group of this lane's experts

  for (int m = wid; m < BM; m += 8) {
    float v[4];
    *reinterpret_cast<float4*>(v) =
        *reinterpret_cast<const float4*>(&sm.Sc[m][lane * 4]);

    // softmax (match jax: subtract row max, exp, divide by sum)
    float mx = fmaxf(fmaxf(v[0], v[1]), fmaxf(v[2], v[3]));
    #pragma unroll
    for (int s = 1; s < 64; s <<= 1) mx = fmaxf(mx, __shfl_xor(mx, s));
    float ex[4], sum = 0.f;
    #pragma unroll
    for (int j = 0; j < 4; ++j) { ex[j] = expf(v[j] - mx); sum += ex[j]; }
    #pragma unroll
    for (int s = 1; s < 64; s <<= 1) sum += __shfl_xor(sum, s);
    float sc[4], sel[4];
    sc[0] = ex[0] / sum; sc[1] = ex[1] / sum;
    sc[2] = ex[2] / sum; sc[3] = ex[3] / sum;
    sel[0] = sc[0] + bsl.x; sel[1] = sc[1] + bsl.y;
    sel[2] = sc[2] + bsl.z; sel[3] = sc[3] + bsl.w;

    // keep original scores for the gather
    *reinterpret_cast<float4*>(&sm.Sc[m][lane * 4]) =
        make_float4(sc[0], sc[1], sc[2], sc[3]);

    // group max (groups of 32 experts = 8 lanes)
    float gv = fmaxf(fmaxf(sel[0], sel[1]), fmaxf(sel[2], sel[3]));
    gv = fmaxf(gv, __shfl_xor(gv, 1));
    gv = fmaxf(gv, __shfl_xor(gv, 2));
    gv = fmaxf(gv, __shfl_xor(gv, 4));

    // top-4 groups, tie -> lower group index (jax.lax.top_k stability)
    unsigned gmask = 0;
    float gcur = gv;
    #pragma unroll
    for (int it = 0; it < NLIM; ++it) {
      float bv2 = gcur; int bi = g;
      #pragma unroll
      for (int s = 1; s < 64; s <<= 1) {
        float ov = __shfl_xor(bv2, s);
        int   oi = __shfl_xor(bi, s);
        if (ov > bv2 || (ov == bv2 && oi < bi)) { bv2 = ov; bi = oi; }
      }
      gmask |= 1u << bi;
      if (g == bi) gcur = -INFINITY;
    }
    if (!((gmask >> g) & 1u)) {
      sel[0] = sel[1] = sel[2] = sel[3] = -INFINITY;
    }

    // top-8 experts, tie -> lower expert index
    const int gtok = row0 + m;
    #pragma unroll
    for (int it = 0; it < TOPK; ++it) {
      float bv2 = sel[0]; int bi = lane * 4;
      #pragma unroll
      for (int j = 1; j < 4; ++j)
        if (sel[j] > bv2) { bv2 = sel[j]; bi = lane * 4 + j; }
      #pragma unroll
      for (int s = 1; s < 64; s <<= 1) {
        float ov = __shfl_xor(bv2, s);
        int   oi = __shfl_xor(bi, s);
        if (ov > bv2 || (ov == bv2 && oi < bi)) { bv2 = ov; bi = oi; }
      }
      if (lane == 0) {
        out_w[(size_t)gtok * TOPK + it]   = sm.Sc[m][bi] * 2.5f;
        out_idx[(size_t)gtok * TOPK + it] = (float)bi;
        atomicAdd(&hist[bi], 1);
      }
      if ((bi >> 2) == lane) sel[bi & 3] = -INFINITY;
    }
  }

  __syncthreads();
  for (int b = tid; b < NEXP; b += NTHREADS)
    if (hist[b]) atomicAdd(&out_load[b], (float)hist[b]);
}

extern "C" void kernel_launch(void* const* d_in, const int* in_sizes, int n_in,
                              void* d_out, int out_size, void* d_ws, size_t ws_size,
                              hipStream_t stream) {
  const float* x    = (const float*)d_in[0];
  const float* w    = (const float*)d_in[1];
  const float* bias = (const float*)d_in[2];
  float* out_w    = (float*)d_out;
  float* out_idx  = out_w + (size_t)T_TOKENS * TOPK;
  float* out_load = out_idx + (size_t)T_TOKENS * TOPK;
  unsigned short* wfrag = (unsigned short*)d_ws;   // 1 MB fragment-ordered fp16 w

  (void)hipMemsetAsync(out_load, 0, NEXP * sizeof(float), stream);
  prep_w<<<256, 256, 0, stream>>>(w, wfrag);
  gate_kernel<<<T_TOKENS / BM, NTHREADS, 0, stream>>>(
      x, wfrag, bias, out_w, out_idx, out_load);
}